// Round 5
// baseline (359.555 us; speedup 1.0000x reference)
//
#include <hip/hip_runtime.h>
#include <math.h>

// AutoLUT forward, MI355X. B=4, N=512, K=3 (PAD=2), Q=16, L=17, UPSCALE=4, SAMPLERS=3.
// R5: stage0 batches all 20 gathers per sampler (latency MLP); stage1 LUT in f16
//     (exact for int8 values) consumed via float(f16)*f32+f32 -> v_fma_mix_f32.
static constexpr int B_ = 4;
static constexpr int N_ = 512;
static constexpr int N4_ = 2048;
static constexpr int LUT_ROWS = 83521;         // 17^4
static constexpr int ST0 = 4913, ST1 = 289, ST2 = 17, ST3 = 1;

__device__ __forceinline__ float fixw(float v) {
    v = rintf(v * 127.0f);
    return fminf(fmaxf(v, -127.0f), 127.0f);
}

__global__ void fix_lut0_kernel(const float* __restrict__ in, char* __restrict__ out, int n) {
    int t = blockIdx.x * blockDim.x + threadIdx.x;
    if (t < n) out[t] = (char)(int)fixw(in[t]);
}

__global__ void fix_lut1_kernel(const float4* __restrict__ in, _Float16* __restrict__ out, int n4) {
    int t = blockIdx.x * blockDim.x + threadIdx.x;
    if (t < n4) {
        float4 v = in[t];
        _Float16* o = out + (size_t)t * 4;
        o[0] = (_Float16)fixw(v.x);    // int values in [-127,127]: exact in f16
        o[1] = (_Float16)fixw(v.y);
        o[2] = (_Float16)fixw(v.z);
        o[3] = (_Float16)fixw(v.w);
    }
}

struct Simplex {
    int v[5];
    float w[5];   // pre-scaled by 1/16
};

// 4-D simplex lookup setup. floor/mod by 16 are exact in fp32 (pow-2); sort is a
// stable descending bubble network (ties -> zero-weight vertices, order-irrelevant).
__device__ __forceinline__ Simplex simplex4(float a, float b, float c, float d) {
    float fl0 = floorf(a * 0.0625f), fl1 = floorf(b * 0.0625f),
          fl2 = floorf(c * 0.0625f), fl3 = floorf(d * 0.0625f);
    float f[4] = { a - 16.0f * fl0, b - 16.0f * fl1, c - 16.0f * fl2, d - 16.0f * fl3 };
    int l0 = min(max((int)fl0, 0), 15);
    int l1 = min(max((int)fl1, 0), 15);
    int l2 = min(max((int)fl2, 0), 15);
    int l3 = min(max((int)fl3, 0), 15);
    int st[4] = { ST0, ST1, ST2, ST3 };
#define CSW(A, Bq) { if (f[A] < f[Bq]) { float tf = f[A]; f[A] = f[Bq]; f[Bq] = tf; \
                                         int ts = st[A]; st[A] = st[Bq]; st[Bq] = ts; } }
    CSW(0, 1) CSW(1, 2) CSW(2, 3) CSW(0, 1) CSW(1, 2) CSW(0, 1)
#undef CSW
    Simplex s;
    s.v[0] = l0 * ST0 + l1 * ST1 + l2 * ST2 + l3;
    s.v[1] = s.v[0] + st[0];
    s.v[2] = s.v[1] + st[1];
    s.v[3] = s.v[2] + st[2];
    s.v[4] = s.v[3] + st[3];
    s.w[0] = (16.0f - f[0]) * 0.0625f;
    s.w[1] = (f[0] - f[1]) * 0.0625f;
    s.w[2] = (f[1] - f[2]) * 0.0625f;
    s.w[3] = (f[2] - f[3]) * 0.0625f;
    s.w[4] = f[3] * 0.0625f;
    return s;
}

// Inverse tap map: which (di,dj) of rotation r reads clamped-neighborhood tap (a,c).
// (rotation r + edge-pad + VALID conv + rotate-back == clamped reads, orig frame)
__device__ __forceinline__ bool tap_for_r(int r, int a, int c, int& di, int& dj) {
    if (r == 0) { di = a - 2; dj = c - 2; return (a >= 2) && (c >= 2); }
    if (r == 1) { di = 2 - c; dj = a - 2; return (a >= 2) && (c <= 2); }
    if (r == 2) { di = 2 - a; dj = 2 - c; return (a <= 2) && (c <= 2); }
    di = c - 2; dj = 2 - a; return (a <= 2) && (c >= 2);
}

__global__ __launch_bounds__(256) void stage0_kernel(
    const float* __restrict__ x,       // (4,512,512), [0,1]
    const char* __restrict__ lut0q,    // (3,83521) int8 fixed
    const float* __restrict__ samp0,   // (3,4,3,3)
    const float* __restrict__ sbias0,  // (3,4)
    float* __restrict__ x1)            // out: (4,512,512), integer-valued 0..255
{
    int tid = blockIdx.x * blockDim.x + threadIdx.x;
    if (tid >= B_ * N_ * N_) return;
    int j = tid & (N_ - 1);
    int i = (tid >> 9) & (N_ - 1);
    int b = tid >> 18;
    const float* xb = x + (size_t)b * N_ * N_;

    float pred = 0.0f;
    for (int s = 0; s < 3; ++s) {
        const float* w  = samp0 + s * 36;
        const float* sb = sbias0 + s * 4;
        const char* lut = lut0q + (size_t)s * LUT_ROWS;

        // tap-outer conv: only 1 pixel + 16 accumulators live
        float vals[4][4];
        #pragma unroll
        for (int r = 0; r < 4; ++r)
            #pragma unroll
            for (int ch = 0; ch < 4; ++ch) vals[r][ch] = 0.0f;
        #pragma unroll
        for (int a = 0; a < 5; ++a) {
            int ri = min(max(i - 2 + a, 0), N_ - 1);
            #pragma unroll
            for (int c = 0; c < 5; ++c) {
                int ci = min(max(j - 2 + c, 0), N_ - 1);
                float px = xb[ri * N_ + ci] * 255.0f;
                #pragma unroll
                for (int r = 0; r < 4; ++r) {
                    int di, dj;
                    if (tap_for_r(r, a, c, di, dj)) {
                        #pragma unroll
                        for (int ch = 0; ch < 4; ++ch)
                            vals[r][ch] += w[ch * 9 + di * 3 + dj] * px;
                    }
                }
            }
        }

        // all 4 rotations' simplexes, then 20 independent gathers in flight
        int vidx[20];
        float vw[20];
        #pragma unroll
        for (int r = 0; r < 4; ++r) {
            Simplex sx = simplex4(vals[r][0] + sb[0], vals[r][1] + sb[1],
                                  vals[r][2] + sb[2], vals[r][3] + sb[3]);
            #pragma unroll
            for (int v = 0; v < 5; ++v) { vidx[r * 5 + v] = sx.v[v]; vw[r * 5 + v] = sx.w[v]; }
        }
        float pv[20];
        #pragma unroll
        for (int t = 0; t < 20; ++t) pv[t] = (float)lut[vidx[t]];

        float acc = 0.0f;
        #pragma unroll
        for (int r = 0; r < 4; ++r) {
            float o = vw[r * 5 + 0] * pv[r * 5 + 0];
            #pragma unroll
            for (int v = 1; v < 5; ++v) o += vw[r * 5 + v] * pv[r * 5 + v];
            acc = rintf(acc + o);   // ste_round after each rotation
        }
        pred += acc;
    }
    x1[tid] = rintf(fminf(fmaxf(pred / 12.0f + 127.0f, 0.0f), 255.0f));
}

__global__ __launch_bounds__(256) void stage1_kernel(
    const float* __restrict__ x,        // original (4,512,512), [0,1]
    const float* __restrict__ x1,       // stage-0 out, 0..255
    const _Float16* __restrict__ lut1h, // (3,83521,16) f16 fixed
    const float* __restrict__ samp1,    // (3,4,3,3)
    const float* __restrict__ sbias1,   // (3,4)
    const float* __restrict__ resw1,    // (3,2,2)
    float* __restrict__ out)            // (4,2048,2048)
{
    int tid = blockIdx.x * blockDim.x + threadIdx.x;
    if (tid >= B_ * N_ * N_) return;
    int j = tid & (N_ - 1);
    int i = (tid >> 9) & (N_ - 1);
    int b = tid >> 18;
    const float* xb  = x  + (size_t)b * N_ * N_;
    const float* x1b = x1 + (size_t)b * N_ * N_;

    float tot[16];
    #pragma unroll
    for (int k = 0; k < 16; ++k) tot[k] = 0.0f;

    for (int s = 0; s < 3; ++s) {
        const float* w  = samp1 + s * 36;
        const float* sb = sbias1 + s * 4;
        const _Float16* lut = lut1h + (size_t)s * LUT_ROWS * 16;
        float rw[4];
        #pragma unroll
        for (int ch = 0; ch < 4; ++ch)
            rw[ch] = fminf(fmaxf(resw1[s * 4 + ch], 0.0f), 1.0f);

        // ---- tap-outer conv: 2 live pixels + 32 accumulators (vc, vp raw[0,1])
        float vc[4][4], vp[4][4];
        #pragma unroll
        for (int r = 0; r < 4; ++r)
            #pragma unroll
            for (int ch = 0; ch < 4; ++ch) { vc[r][ch] = 0.0f; vp[r][ch] = 0.0f; }
        #pragma unroll
        for (int a = 0; a < 5; ++a) {
            int ri = min(max(i - 2 + a, 0), N_ - 1);
            #pragma unroll
            for (int c = 0; c < 5; ++c) {
                int ci = min(max(j - 2 + c, 0), N_ - 1);
                float pc = x1b[ri * N_ + ci];
                float pr = xb[ri * N_ + ci];          // raw [0,1]; x255 folded below
                #pragma unroll
                for (int r = 0; r < 4; ++r) {
                    int di, dj;
                    if (tap_for_r(r, a, c, di, dj)) {
                        #pragma unroll
                        for (int ch = 0; ch < 4; ++ch) {
                            float wt = w[ch * 9 + di * 3 + dj];
                            vc[r][ch] += wt * pc;
                            vp[r][ch] += wt * pr;
                        }
                    }
                }
            }
        }

        // ---- gather/interp phase
        float acc[16];
        #pragma unroll
        for (int k = 0; k < 16; ++k) acc[k] = 0.0f;

        #pragma unroll
        for (int r = 0; r < 4; ++r) {
            float vals[4];
            #pragma unroll
            for (int ch = 0; ch < 4; ++ch) {
                // rw*(255*vp_raw + sb) + (1-rw)*(vc + sb)
                //   = (vc + sb) + rw * (255*vp_raw - vc)
                float t  = fmaf(255.0f, vp[r][ch], -vc[r][ch]);
                vals[ch] = fmaf(rw[ch], t, vc[r][ch] + sb[ch]);
            }
            Simplex sx = simplex4(vals[0], vals[1], vals[2], vals[3]);
            float oc[16];
            #pragma unroll
            for (int k = 0; k < 16; ++k) oc[k] = 0.0f;
            #pragma unroll
            for (int v = 0; v < 5; ++v) {
                union { int4 q[2]; _Float16 h[16]; } u;
                const int4* rp = (const int4*)(lut + (size_t)sx.v[v] * 16);
                u.q[0] = rp[0];
                u.q[1] = rp[1];
                float wv = sx.w[v];
                #pragma unroll
                for (int k = 0; k < 16; ++k)
                    oc[k] = fmaf(wv, (float)u.h[k], oc[k]);   // -> v_fma_mix_f32
            }
            // scatter rotated 4x4 sub-block into original-orientation accumulator
            #pragma unroll
            for (int u2 = 0; u2 < 4; ++u2)
                #pragma unroll
                for (int v2 = 0; v2 < 4; ++v2) {
                    int k = 4 * u2 + v2;
                    int c = (r == 0) ? (4 * u2 + v2)
                          : (r == 1) ? (4 * (3 - v2) + u2)
                          : (r == 2) ? (4 * (3 - u2) + (3 - v2))
                                     : (4 * v2 + (3 - u2));
                    acc[k] = rintf(acc[k] + oc[c]);   // ste_round per rotation
                }
        }
        #pragma unroll
        for (int k = 0; k < 16; ++k) tot[k] += acc[k];
    }

    float* ob = out + (size_t)b * N4_ * N4_ + (size_t)(i * 4) * N4_ + (j * 4);
    #pragma unroll
    for (int u = 0; u < 4; ++u) {
        float4 val;
        val.x = rintf(fminf(fmaxf(tot[4 * u + 0] / 3.0f, 0.0f), 255.0f)) * (1.0f / 255.0f);
        val.y = rintf(fminf(fmaxf(tot[4 * u + 1] / 3.0f, 0.0f), 255.0f)) * (1.0f / 255.0f);
        val.z = rintf(fminf(fmaxf(tot[4 * u + 2] / 3.0f, 0.0f), 255.0f)) * (1.0f / 255.0f);
        val.w = rintf(fminf(fmaxf(tot[4 * u + 3] / 3.0f, 0.0f), 255.0f)) * (1.0f / 255.0f);
        *(float4*)(ob + (size_t)u * N4_) = val;
    }
}

extern "C" void kernel_launch(void* const* d_in, const int* in_sizes, int n_in,
                              void* d_out, int out_size, void* d_ws, size_t ws_size,
                              hipStream_t stream) {
    const float* x      = (const float*)d_in[0];
    const float* lut0   = (const float*)d_in[1];
    const float* lut1   = (const float*)d_in[2];
    const float* samp0  = (const float*)d_in[3];
    const float* samp1  = (const float*)d_in[4];
    const float* sbias0 = (const float*)d_in[5];
    const float* sbias1 = (const float*)d_in[6];
    const float* resw1  = (const float*)d_in[7];
    float* out = (float*)d_out;
    char* ws   = (char*)d_ws;

    const int N_L0 = 3 * LUT_ROWS;            // 250,563
    const int N_L1 = 3 * LUT_ROWS * 16;       // 4,009,008
    size_t off_x1 = 0;                        // 4 MB of floats
    size_t off_l0 = (size_t)B_ * N_ * N_ * sizeof(float);
    size_t off_l1 = (off_l0 + N_L0 + 31) & ~(size_t)31;   // f16 rows, 32B aligned

    float* x1 = (float*)(ws + off_x1);
    char* l0q = ws + off_l0;
    _Float16* l1h = (_Float16*)(ws + off_l1);             // 8 MB

    const int threads = 256;
    const int grid = (B_ * N_ * N_) / threads;    // 4096

    fix_lut0_kernel<<<(N_L0 + threads - 1) / threads, threads, 0, stream>>>(lut0, l0q, N_L0);
    fix_lut1_kernel<<<(N_L1 / 4 + threads - 1) / threads, threads, 0, stream>>>(
        (const float4*)lut1, l1h, N_L1 / 4);
    stage0_kernel<<<grid, threads, 0, stream>>>(x, l0q, samp0, sbias0, x1);
    stage1_kernel<<<grid, threads, 0, stream>>>(x, x1, l1h, samp1, sbias1, resw1, out);
}

// Round 6
// 344.274 us; speedup vs baseline: 1.0444x; 1.0444x over previous
//
#include <hip/hip_runtime.h>
#include <math.h>

// AutoLUT forward, MI355X. B=4, N=512, K=3 (PAD=2), Q=16, L=17, UPSCALE=4, SAMPLERS=3.
// R6: stage1 = R4 int8 form (proven 158us). stage0 split by sampler into 3M threads
//     with fp32 atomicAdd (exact: per-sampler accs are integers) + finalize kernel.
static constexpr int B_ = 4;
static constexpr int N_ = 512;
static constexpr int N4_ = 2048;
static constexpr int NPIX = B_ * N_ * N_;      // 2^20
static constexpr int LUT_ROWS = 83521;         // 17^4
static constexpr int ST0 = 4913, ST1 = 289, ST2 = 17, ST3 = 1;

__device__ __forceinline__ float fixw(float v) {
    v = rintf(v * 127.0f);
    return fminf(fmaxf(v, -127.0f), 127.0f);
}

__global__ void fix_lut0_kernel(const float* __restrict__ in, char* __restrict__ out, int n) {
    int t = blockIdx.x * blockDim.x + threadIdx.x;
    if (t < n) out[t] = (char)(int)fixw(in[t]);
}

__global__ void fix_lut1_kernel(const float4* __restrict__ in, char4* __restrict__ out, int n4) {
    int t = blockIdx.x * blockDim.x + threadIdx.x;
    if (t < n4) {
        float4 v = in[t];
        char4 o;
        o.x = (char)(int)fixw(v.x);
        o.y = (char)(int)fixw(v.y);
        o.z = (char)(int)fixw(v.z);
        o.w = (char)(int)fixw(v.w);
        out[t] = o;
    }
}

struct Simplex {
    int v[5];
    float w[5];   // pre-scaled by 1/16
};

// 4-D simplex lookup setup. floor/mod by 16 are exact in fp32 (pow-2); sort is a
// stable descending bubble network (ties -> zero-weight vertices, order-irrelevant).
__device__ __forceinline__ Simplex simplex4(float a, float b, float c, float d) {
    float fl0 = floorf(a * 0.0625f), fl1 = floorf(b * 0.0625f),
          fl2 = floorf(c * 0.0625f), fl3 = floorf(d * 0.0625f);
    float f[4] = { a - 16.0f * fl0, b - 16.0f * fl1, c - 16.0f * fl2, d - 16.0f * fl3 };
    int l0 = min(max((int)fl0, 0), 15);
    int l1 = min(max((int)fl1, 0), 15);
    int l2 = min(max((int)fl2, 0), 15);
    int l3 = min(max((int)fl3, 0), 15);
    int st[4] = { ST0, ST1, ST2, ST3 };
#define CSW(A, Bq) { if (f[A] < f[Bq]) { float tf = f[A]; f[A] = f[Bq]; f[Bq] = tf; \
                                         int ts = st[A]; st[A] = st[Bq]; st[Bq] = ts; } }
    CSW(0, 1) CSW(1, 2) CSW(2, 3) CSW(0, 1) CSW(1, 2) CSW(0, 1)
#undef CSW
    Simplex s;
    s.v[0] = l0 * ST0 + l1 * ST1 + l2 * ST2 + l3;
    s.v[1] = s.v[0] + st[0];
    s.v[2] = s.v[1] + st[1];
    s.v[3] = s.v[2] + st[2];
    s.v[4] = s.v[3] + st[3];
    s.w[0] = (16.0f - f[0]) * 0.0625f;
    s.w[1] = (f[0] - f[1]) * 0.0625f;
    s.w[2] = (f[1] - f[2]) * 0.0625f;
    s.w[3] = (f[2] - f[3]) * 0.0625f;
    s.w[4] = f[3] * 0.0625f;
    return s;
}

// Inverse tap map: which (di,dj) of rotation r reads clamped-neighborhood tap (a,c).
// (rotation r + edge-pad + VALID conv + rotate-back == clamped reads, orig frame)
__device__ __forceinline__ bool tap_for_r(int r, int a, int c, int& di, int& dj) {
    if (r == 0) { di = a - 2; dj = c - 2; return (a >= 2) && (c >= 2); }
    if (r == 1) { di = 2 - c; dj = a - 2; return (a >= 2) && (c <= 2); }
    if (r == 2) { di = 2 - a; dj = 2 - c; return (a <= 2) && (c <= 2); }
    di = c - 2; dj = 2 - a; return (a <= 2) && (c >= 2);
}

__device__ __forceinline__ void unpack4(int w, float* o) {
    o[0] = (float)((w << 24) >> 24);
    o[1] = (float)((w << 16) >> 24);
    o[2] = (float)((w << 8) >> 24);
    o[3] = (float)(w >> 24);
}

// One (pixel, sampler) per thread: 3M threads, ~3x the gathers in flight vs R4.
__global__ __launch_bounds__(256) void stage0_split_kernel(
    const float* __restrict__ x,       // (4,512,512), [0,1]
    const char* __restrict__ lut0q,    // (3,83521) int8 fixed
    const float* __restrict__ samp0,   // (3,4,3,3)
    const float* __restrict__ sbias0,  // (3,4)
    float* __restrict__ x1acc)         // pre-zeroed; accumulates integer-valued accs
{
    int tid = blockIdx.x * blockDim.x + threadIdx.x;
    int pix = tid & (NPIX - 1);
    int s = tid >> 20;                 // wave-uniform (blocks of one sampler)
    int j = pix & (N_ - 1);
    int i = (pix >> 9) & (N_ - 1);
    int b = pix >> 18;
    const float* xb = x + (size_t)b * N_ * N_;
    const float* w  = samp0 + s * 36;
    const float* sb = sbias0 + s * 4;
    const char* lut = lut0q + (size_t)s * LUT_ROWS;

    // tap-outer conv: only 1 pixel + 16 accumulators live
    float vals[4][4];
    #pragma unroll
    for (int r = 0; r < 4; ++r)
        #pragma unroll
        for (int ch = 0; ch < 4; ++ch) vals[r][ch] = 0.0f;
    #pragma unroll
    for (int a = 0; a < 5; ++a) {
        int ri = min(max(i - 2 + a, 0), N_ - 1);
        #pragma unroll
        for (int c = 0; c < 5; ++c) {
            int ci = min(max(j - 2 + c, 0), N_ - 1);
            float px = xb[ri * N_ + ci] * 255.0f;
            #pragma unroll
            for (int r = 0; r < 4; ++r) {
                int di, dj;
                if (tap_for_r(r, a, c, di, dj)) {
                    #pragma unroll
                    for (int ch = 0; ch < 4; ++ch)
                        vals[r][ch] += w[ch * 9 + di * 3 + dj] * px;
                }
            }
        }
    }

    // all 4 rotations' simplexes, then 20 independent byte gathers in flight
    int vidx[20];
    float vw[20];
    #pragma unroll
    for (int r = 0; r < 4; ++r) {
        Simplex sx = simplex4(vals[r][0] + sb[0], vals[r][1] + sb[1],
                              vals[r][2] + sb[2], vals[r][3] + sb[3]);
        #pragma unroll
        for (int v = 0; v < 5; ++v) { vidx[r * 5 + v] = sx.v[v]; vw[r * 5 + v] = sx.w[v]; }
    }
    float pv[20];
    #pragma unroll
    for (int t = 0; t < 20; ++t) pv[t] = (float)lut[vidx[t]];

    float acc = 0.0f;
    #pragma unroll
    for (int r = 0; r < 4; ++r) {
        float o = vw[r * 5 + 0] * pv[r * 5 + 0];
        #pragma unroll
        for (int v = 1; v < 5; ++v) o += vw[r * 5 + v] * pv[r * 5 + v];
        acc = rintf(acc + o);   // ste_round after each rotation -> integer-valued
    }
    atomicAdd(&x1acc[pix], acc);   // sum of 3 integers: exact, order-independent
}

__global__ void stage0_fin_kernel(float* __restrict__ x1) {
    int t = blockIdx.x * blockDim.x + threadIdx.x;
    if (t < NPIX) {
        float pred = x1[t];
        x1[t] = rintf(fminf(fmaxf(pred / 12.0f + 127.0f, 0.0f), 255.0f));
    }
}

__global__ __launch_bounds__(256) void stage1_kernel(
    const float* __restrict__ x,       // original (4,512,512), [0,1]
    const float* __restrict__ x1,      // stage-0 out, 0..255
    const char* __restrict__ lut1q,    // (3,83521,16) int8 fixed
    const float* __restrict__ samp1,   // (3,4,3,3)
    const float* __restrict__ sbias1,  // (3,4)
    const float* __restrict__ resw1,   // (3,2,2)
    float* __restrict__ out)           // (4,2048,2048)
{
    int tid = blockIdx.x * blockDim.x + threadIdx.x;
    if (tid >= NPIX) return;
    int j = tid & (N_ - 1);
    int i = (tid >> 9) & (N_ - 1);
    int b = tid >> 18;
    const float* xb  = x  + (size_t)b * N_ * N_;
    const float* x1b = x1 + (size_t)b * N_ * N_;

    float tot[16];
    #pragma unroll
    for (int k = 0; k < 16; ++k) tot[k] = 0.0f;

    for (int s = 0; s < 3; ++s) {
        const float* w  = samp1 + s * 36;
        const float* sb = sbias1 + s * 4;
        const char* lut = lut1q + (size_t)s * LUT_ROWS * 16;
        float rw[4];
        #pragma unroll
        for (int ch = 0; ch < 4; ++ch)
            rw[ch] = fminf(fmaxf(resw1[s * 4 + ch], 0.0f), 1.0f);

        // ---- tap-outer conv: 2 live pixels + 32 accumulators (vc, vp)
        float vc[4][4], vp[4][4];
        #pragma unroll
        for (int r = 0; r < 4; ++r)
            #pragma unroll
            for (int ch = 0; ch < 4; ++ch) { vc[r][ch] = 0.0f; vp[r][ch] = 0.0f; }
        #pragma unroll
        for (int a = 0; a < 5; ++a) {
            int ri = min(max(i - 2 + a, 0), N_ - 1);
            #pragma unroll
            for (int c = 0; c < 5; ++c) {
                int ci = min(max(j - 2 + c, 0), N_ - 1);
                float pc = x1b[ri * N_ + ci];
                float pp = xb[ri * N_ + ci] * 255.0f;
                #pragma unroll
                for (int r = 0; r < 4; ++r) {
                    int di, dj;
                    if (tap_for_r(r, a, c, di, dj)) {
                        #pragma unroll
                        for (int ch = 0; ch < 4; ++ch) {
                            float wt = w[ch * 9 + di * 3 + dj];
                            vc[r][ch] += wt * pc;
                            vp[r][ch] += wt * pp;
                        }
                    }
                }
            }
        }

        // ---- gather/interp phase
        float acc[16];
        #pragma unroll
        for (int k = 0; k < 16; ++k) acc[k] = 0.0f;

        #pragma unroll
        for (int r = 0; r < 4; ++r) {
            float vals[4];
            #pragma unroll
            for (int ch = 0; ch < 4; ++ch)
                vals[ch] = rw[ch] * (vp[r][ch] + sb[ch])
                         + (1.0f - rw[ch]) * (vc[r][ch] + sb[ch]);
            Simplex sx = simplex4(vals[0], vals[1], vals[2], vals[3]);
            float oc[16];
            #pragma unroll
            for (int k = 0; k < 16; ++k) oc[k] = 0.0f;
            #pragma unroll
            for (int v = 0; v < 5; ++v) {
                const int4 q = *(const int4*)(lut + (size_t)sx.v[v] * 16);
                float p[16];
                unpack4(q.x, p); unpack4(q.y, p + 4);
                unpack4(q.z, p + 8); unpack4(q.w, p + 12);
                float wv = sx.w[v];
                #pragma unroll
                for (int k = 0; k < 16; ++k) oc[k] += wv * p[k];
            }
            // scatter rotated 4x4 sub-block into original-orientation accumulator
            #pragma unroll
            for (int u = 0; u < 4; ++u)
                #pragma unroll
                for (int v2 = 0; v2 < 4; ++v2) {
                    int k = 4 * u + v2;
                    int c = (r == 0) ? (4 * u + v2)
                          : (r == 1) ? (4 * (3 - v2) + u)
                          : (r == 2) ? (4 * (3 - u) + (3 - v2))
                                     : (4 * v2 + (3 - u));
                    acc[k] = rintf(acc[k] + oc[c]);   // ste_round per rotation
                }
        }
        #pragma unroll
        for (int k = 0; k < 16; ++k) tot[k] += acc[k];
    }

    float* ob = out + (size_t)b * N4_ * N4_ + (size_t)(i * 4) * N4_ + (j * 4);
    #pragma unroll
    for (int u = 0; u < 4; ++u) {
        float4 val;
        val.x = rintf(fminf(fmaxf(tot[4 * u + 0] / 3.0f, 0.0f), 255.0f)) * (1.0f / 255.0f);
        val.y = rintf(fminf(fmaxf(tot[4 * u + 1] / 3.0f, 0.0f), 255.0f)) * (1.0f / 255.0f);
        val.z = rintf(fminf(fmaxf(tot[4 * u + 2] / 3.0f, 0.0f), 255.0f)) * (1.0f / 255.0f);
        val.w = rintf(fminf(fmaxf(tot[4 * u + 3] / 3.0f, 0.0f), 255.0f)) * (1.0f / 255.0f);
        *(float4*)(ob + (size_t)u * N4_) = val;
    }
}

extern "C" void kernel_launch(void* const* d_in, const int* in_sizes, int n_in,
                              void* d_out, int out_size, void* d_ws, size_t ws_size,
                              hipStream_t stream) {
    const float* x      = (const float*)d_in[0];
    const float* lut0   = (const float*)d_in[1];
    const float* lut1   = (const float*)d_in[2];
    const float* samp0  = (const float*)d_in[3];
    const float* samp1  = (const float*)d_in[4];
    const float* sbias0 = (const float*)d_in[5];
    const float* sbias1 = (const float*)d_in[6];
    const float* resw1  = (const float*)d_in[7];
    float* out = (float*)d_out;
    char* ws   = (char*)d_ws;

    const int N_L0 = 3 * LUT_ROWS;            // 250,563
    const int N_L1 = 3 * LUT_ROWS * 16;       // 4,009,008
    size_t off_x1 = 0;                        // 4 MB of floats
    size_t off_l0 = (size_t)NPIX * sizeof(float);
    size_t off_l1 = (off_l0 + N_L0 + 15) & ~(size_t)15;

    float* x1 = (float*)(ws + off_x1);
    char* l0q = ws + off_l0;
    char* l1q = ws + off_l1;

    const int threads = 256;
    const int grid = NPIX / threads;              // 4096

    hipMemsetAsync(x1, 0, (size_t)NPIX * sizeof(float), stream);
    fix_lut0_kernel<<<(N_L0 + threads - 1) / threads, threads, 0, stream>>>(lut0, l0q, N_L0);
    fix_lut1_kernel<<<(N_L1 / 4 + threads - 1) / threads, threads, 0, stream>>>(
        (const float4*)lut1, (char4*)l1q, N_L1 / 4);
    stage0_split_kernel<<<3 * grid, threads, 0, stream>>>(x, l0q, samp0, sbias0, x1);
    stage0_fin_kernel<<<grid, threads, 0, stream>>>(x1);
    stage1_kernel<<<grid, threads, 0, stream>>>(x, x1, l1q, samp1, sbias1, resw1, out);
}

// Round 7
// 316.597 us; speedup vs baseline: 1.1357x; 1.0874x over previous
//
#include <hip/hip_runtime.h>
#include <math.h>

// AutoLUT forward, MI355X. B=4, N=512, K=3 (PAD=2), Q=16, L=17, UPSCALE=4, SAMPLERS=3.
// R7: stage0 LUT staged in LDS (83.5KB/sampler, gfx950 has 160KB/CU) -> kills the
//     ~3.8GB of L2 line-granularity gather traffic that bounded stage0.
//     stage1 = unchanged R4/R6 int8 form (proven 158us).
static constexpr int B_ = 4;
static constexpr int N_ = 512;
static constexpr int N4_ = 2048;
static constexpr int NPIX = B_ * N_ * N_;      // 2^20
static constexpr int LUT_ROWS = 83521;         // 17^4
static constexpr int SPAD = 83584;             // LUT_ROWS padded to 16B multiple
static constexpr int ST0 = 4913, ST1 = 289, ST2 = 17, ST3 = 1;

__device__ __forceinline__ float fixw(float v) {
    v = rintf(v * 127.0f);
    return fminf(fmaxf(v, -127.0f), 127.0f);
}

// (3,83521) -> int8 with 16B-aligned per-sampler stride SPAD
__global__ void fix_lut0_kernel(const float* __restrict__ in, char* __restrict__ out) {
    int t = blockIdx.x * blockDim.x + threadIdx.x;
    int s = blockIdx.y;
    if (t < LUT_ROWS) out[(size_t)s * SPAD + t] = (char)(int)fixw(in[(size_t)s * LUT_ROWS + t]);
}

__global__ void fix_lut1_kernel(const float4* __restrict__ in, char4* __restrict__ out, int n4) {
    int t = blockIdx.x * blockDim.x + threadIdx.x;
    if (t < n4) {
        float4 v = in[t];
        char4 o;
        o.x = (char)(int)fixw(v.x);
        o.y = (char)(int)fixw(v.y);
        o.z = (char)(int)fixw(v.z);
        o.w = (char)(int)fixw(v.w);
        out[t] = o;
    }
}

struct Simplex {
    int v[5];
    float w[5];   // pre-scaled by 1/16
};

// 4-D simplex lookup setup. floor/mod by 16 are exact in fp32 (pow-2); sort is a
// stable descending bubble network (ties -> zero-weight vertices, order-irrelevant).
__device__ __forceinline__ Simplex simplex4(float a, float b, float c, float d) {
    float fl0 = floorf(a * 0.0625f), fl1 = floorf(b * 0.0625f),
          fl2 = floorf(c * 0.0625f), fl3 = floorf(d * 0.0625f);
    float f[4] = { a - 16.0f * fl0, b - 16.0f * fl1, c - 16.0f * fl2, d - 16.0f * fl3 };
    int l0 = min(max((int)fl0, 0), 15);
    int l1 = min(max((int)fl1, 0), 15);
    int l2 = min(max((int)fl2, 0), 15);
    int l3 = min(max((int)fl3, 0), 15);
    int st[4] = { ST0, ST1, ST2, ST3 };
#define CSW(A, Bq) { if (f[A] < f[Bq]) { float tf = f[A]; f[A] = f[Bq]; f[Bq] = tf; \
                                         int ts = st[A]; st[A] = st[Bq]; st[Bq] = ts; } }
    CSW(0, 1) CSW(1, 2) CSW(2, 3) CSW(0, 1) CSW(1, 2) CSW(0, 1)
#undef CSW
    Simplex s;
    s.v[0] = l0 * ST0 + l1 * ST1 + l2 * ST2 + l3;
    s.v[1] = s.v[0] + st[0];
    s.v[2] = s.v[1] + st[1];
    s.v[3] = s.v[2] + st[2];
    s.v[4] = s.v[3] + st[3];
    s.w[0] = (16.0f - f[0]) * 0.0625f;
    s.w[1] = (f[0] - f[1]) * 0.0625f;
    s.w[2] = (f[1] - f[2]) * 0.0625f;
    s.w[3] = (f[2] - f[3]) * 0.0625f;
    s.w[4] = f[3] * 0.0625f;
    return s;
}

// Inverse tap map: which (di,dj) of rotation r reads clamped-neighborhood tap (a,c).
// (rotation r + edge-pad + VALID conv + rotate-back == clamped reads, orig frame)
__device__ __forceinline__ bool tap_for_r(int r, int a, int c, int& di, int& dj) {
    if (r == 0) { di = a - 2; dj = c - 2; return (a >= 2) && (c >= 2); }
    if (r == 1) { di = 2 - c; dj = a - 2; return (a >= 2) && (c <= 2); }
    if (r == 2) { di = 2 - a; dj = 2 - c; return (a <= 2) && (c <= 2); }
    di = c - 2; dj = 2 - a; return (a <= 2) && (c >= 2);
}

__device__ __forceinline__ void unpack4(int w, float* o) {
    o[0] = (float)((w << 24) >> 24);
    o[1] = (float)((w << 16) >> 24);
    o[2] = (float)((w << 8) >> 24);
    o[3] = (float)(w >> 24);
}

__global__ __launch_bounds__(1024) void stage0_kernel(
    const float* __restrict__ x,       // (4,512,512), [0,1]
    const char* __restrict__ lut0q,    // (3,SPAD) int8 fixed, padded stride
    const float* __restrict__ samp0,   // (3,4,3,3)
    const float* __restrict__ sbias0,  // (3,4)
    float* __restrict__ x1)            // out: (4,512,512), integer-valued 0..255
{
    __shared__ char luts[SPAD];        // one sampler's LUT at a time (83.5KB)

    int tid = blockIdx.x * blockDim.x + threadIdx.x;
    int j = tid & (N_ - 1);
    int i = (tid >> 9) & (N_ - 1);
    int b = tid >> 18;
    const float* xb = x + (size_t)b * N_ * N_;

    float pred = 0.0f;
    for (int s = 0; s < 3; ++s) {
        // ---- stage LUT s into LDS
        __syncthreads();               // previous-iteration readers done
        {
            const int4* src = (const int4*)(lut0q + (size_t)s * SPAD);
            int4* dst = (int4*)luts;
            for (int t = threadIdx.x; t < SPAD / 16; t += 1024) dst[t] = src[t];
        }
        __syncthreads();

        const float* w  = samp0 + s * 36;
        const float* sb = sbias0 + s * 4;

        // tap-outer conv: only 1 pixel + 16 accumulators live
        float vals[4][4];
        #pragma unroll
        for (int r = 0; r < 4; ++r)
            #pragma unroll
            for (int ch = 0; ch < 4; ++ch) vals[r][ch] = 0.0f;
        #pragma unroll
        for (int a = 0; a < 5; ++a) {
            int ri = min(max(i - 2 + a, 0), N_ - 1);
            #pragma unroll
            for (int c = 0; c < 5; ++c) {
                int ci = min(max(j - 2 + c, 0), N_ - 1);
                float px = xb[ri * N_ + ci] * 255.0f;
                #pragma unroll
                for (int r = 0; r < 4; ++r) {
                    int di, dj;
                    if (tap_for_r(r, a, c, di, dj)) {
                        #pragma unroll
                        for (int ch = 0; ch < 4; ++ch)
                            vals[r][ch] += w[ch * 9 + di * 3 + dj] * px;
                    }
                }
            }
        }

        // all 4 rotations' simplexes, then 20 LDS byte-gathers
        int vidx[20];
        float vw[20];
        #pragma unroll
        for (int r = 0; r < 4; ++r) {
            Simplex sx = simplex4(vals[r][0] + sb[0], vals[r][1] + sb[1],
                                  vals[r][2] + sb[2], vals[r][3] + sb[3]);
            #pragma unroll
            for (int v = 0; v < 5; ++v) { vidx[r * 5 + v] = sx.v[v]; vw[r * 5 + v] = sx.w[v]; }
        }
        float pv[20];
        #pragma unroll
        for (int t = 0; t < 20; ++t) pv[t] = (float)luts[vidx[t]];

        float acc = 0.0f;
        #pragma unroll
        for (int r = 0; r < 4; ++r) {
            float o = vw[r * 5 + 0] * pv[r * 5 + 0];
            #pragma unroll
            for (int v = 1; v < 5; ++v) o += vw[r * 5 + v] * pv[r * 5 + v];
            acc = rintf(acc + o);   // ste_round after each rotation
        }
        pred += acc;
    }
    x1[tid] = rintf(fminf(fmaxf(pred / 12.0f + 127.0f, 0.0f), 255.0f));
}

__global__ __launch_bounds__(256) void stage1_kernel(
    const float* __restrict__ x,       // original (4,512,512), [0,1]
    const float* __restrict__ x1,      // stage-0 out, 0..255
    const char* __restrict__ lut1q,    // (3,83521,16) int8 fixed
    const float* __restrict__ samp1,   // (3,4,3,3)
    const float* __restrict__ sbias1,  // (3,4)
    const float* __restrict__ resw1,   // (3,2,2)
    float* __restrict__ out)           // (4,2048,2048)
{
    int tid = blockIdx.x * blockDim.x + threadIdx.x;
    if (tid >= NPIX) return;
    int j = tid & (N_ - 1);
    int i = (tid >> 9) & (N_ - 1);
    int b = tid >> 18;
    const float* xb  = x  + (size_t)b * N_ * N_;
    const float* x1b = x1 + (size_t)b * N_ * N_;

    float tot[16];
    #pragma unroll
    for (int k = 0; k < 16; ++k) tot[k] = 0.0f;

    for (int s = 0; s < 3; ++s) {
        const float* w  = samp1 + s * 36;
        const float* sb = sbias1 + s * 4;
        const char* lut = lut1q + (size_t)s * LUT_ROWS * 16;
        float rw[4];
        #pragma unroll
        for (int ch = 0; ch < 4; ++ch)
            rw[ch] = fminf(fmaxf(resw1[s * 4 + ch], 0.0f), 1.0f);

        // ---- tap-outer conv: 2 live pixels + 32 accumulators (vc, vp)
        float vc[4][4], vp[4][4];
        #pragma unroll
        for (int r = 0; r < 4; ++r)
            #pragma unroll
            for (int ch = 0; ch < 4; ++ch) { vc[r][ch] = 0.0f; vp[r][ch] = 0.0f; }
        #pragma unroll
        for (int a = 0; a < 5; ++a) {
            int ri = min(max(i - 2 + a, 0), N_ - 1);
            #pragma unroll
            for (int c = 0; c < 5; ++c) {
                int ci = min(max(j - 2 + c, 0), N_ - 1);
                float pc = x1b[ri * N_ + ci];
                float pp = xb[ri * N_ + ci] * 255.0f;
                #pragma unroll
                for (int r = 0; r < 4; ++r) {
                    int di, dj;
                    if (tap_for_r(r, a, c, di, dj)) {
                        #pragma unroll
                        for (int ch = 0; ch < 4; ++ch) {
                            float wt = w[ch * 9 + di * 3 + dj];
                            vc[r][ch] += wt * pc;
                            vp[r][ch] += wt * pp;
                        }
                    }
                }
            }
        }

        // ---- gather/interp phase
        float acc[16];
        #pragma unroll
        for (int k = 0; k < 16; ++k) acc[k] = 0.0f;

        #pragma unroll
        for (int r = 0; r < 4; ++r) {
            float vals[4];
            #pragma unroll
            for (int ch = 0; ch < 4; ++ch)
                vals[ch] = rw[ch] * (vp[r][ch] + sb[ch])
                         + (1.0f - rw[ch]) * (vc[r][ch] + sb[ch]);
            Simplex sx = simplex4(vals[0], vals[1], vals[2], vals[3]);
            float oc[16];
            #pragma unroll
            for (int k = 0; k < 16; ++k) oc[k] = 0.0f;
            #pragma unroll
            for (int v = 0; v < 5; ++v) {
                const int4 q = *(const int4*)(lut + (size_t)sx.v[v] * 16);
                float p[16];
                unpack4(q.x, p); unpack4(q.y, p + 4);
                unpack4(q.z, p + 8); unpack4(q.w, p + 12);
                float wv = sx.w[v];
                #pragma unroll
                for (int k = 0; k < 16; ++k) oc[k] += wv * p[k];
            }
            // scatter rotated 4x4 sub-block into original-orientation accumulator
            #pragma unroll
            for (int u = 0; u < 4; ++u)
                #pragma unroll
                for (int v2 = 0; v2 < 4; ++v2) {
                    int k = 4 * u + v2;
                    int c = (r == 0) ? (4 * u + v2)
                          : (r == 1) ? (4 * (3 - v2) + u)
                          : (r == 2) ? (4 * (3 - u) + (3 - v2))
                                     : (4 * v2 + (3 - u));
                    acc[k] = rintf(acc[k] + oc[c]);   // ste_round per rotation
                }
        }
        #pragma unroll
        for (int k = 0; k < 16; ++k) tot[k] += acc[k];
    }

    float* ob = out + (size_t)b * N4_ * N4_ + (size_t)(i * 4) * N4_ + (j * 4);
    #pragma unroll
    for (int u = 0; u < 4; ++u) {
        float4 val;
        val.x = rintf(fminf(fmaxf(tot[4 * u + 0] / 3.0f, 0.0f), 255.0f)) * (1.0f / 255.0f);
        val.y = rintf(fminf(fmaxf(tot[4 * u + 1] / 3.0f, 0.0f), 255.0f)) * (1.0f / 255.0f);
        val.z = rintf(fminf(fmaxf(tot[4 * u + 2] / 3.0f, 0.0f), 255.0f)) * (1.0f / 255.0f);
        val.w = rintf(fminf(fmaxf(tot[4 * u + 3] / 3.0f, 0.0f), 255.0f)) * (1.0f / 255.0f);
        *(float4*)(ob + (size_t)u * N4_) = val;
    }
}

extern "C" void kernel_launch(void* const* d_in, const int* in_sizes, int n_in,
                              void* d_out, int out_size, void* d_ws, size_t ws_size,
                              hipStream_t stream) {
    const float* x      = (const float*)d_in[0];
    const float* lut0   = (const float*)d_in[1];
    const float* lut1   = (const float*)d_in[2];
    const float* samp0  = (const float*)d_in[3];
    const float* samp1  = (const float*)d_in[4];
    const float* sbias0 = (const float*)d_in[5];
    const float* sbias1 = (const float*)d_in[6];
    const float* resw1  = (const float*)d_in[7];
    float* out = (float*)d_out;
    char* ws   = (char*)d_ws;

    const int N_L1 = 3 * LUT_ROWS * 16;       // 4,009,008
    size_t off_x1 = 0;                        // 4 MB of floats
    size_t off_l0 = (size_t)NPIX * sizeof(float);
    size_t off_l1 = (off_l0 + (size_t)3 * SPAD + 15) & ~(size_t)15;

    float* x1 = (float*)(ws + off_x1);
    char* l0q = ws + off_l0;                  // (3, SPAD) padded
    char* l1q = ws + off_l1;

    const int threads = 256;

    dim3 g0((LUT_ROWS + threads - 1) / threads, 3);
    fix_lut0_kernel<<<g0, threads, 0, stream>>>(lut0, l0q);
    fix_lut1_kernel<<<(N_L1 / 4 + threads - 1) / threads, threads, 0, stream>>>(
        (const float4*)lut1, (char4*)l1q, N_L1 / 4);
    stage0_kernel<<<NPIX / 1024, 1024, 0, stream>>>(x, l0q, samp0, sbias0, x1);
    stage1_kernel<<<NPIX / threads, threads, 0, stream>>>(x, x1, l1q, samp1, sbias1, resw1, out);
}

// Round 8
// 298.437 us; speedup vs baseline: 1.2048x; 1.0609x over previous
//
#include <hip/hip_runtime.h>
#include <math.h>

// AutoLUT forward, MI355X. B=4, N=512, K=3 (PAD=2), Q=16, L=17, UPSCALE=4, SAMPLERS=3.
// R8: stage0 LDS LUT kept, but low-register form: per-rotation gathers (5 wide),
//     no 20-wide arrays -> fits 1024-thread VGPR cap without scratch spill
//     (R7 failed on spills: VGPR=64 vs ~90 live, 110MB scratch writes).
//     stage1 = unchanged R4/R6 int8 form (proven ~160us).
static constexpr int B_ = 4;
static constexpr int N_ = 512;
static constexpr int N4_ = 2048;
static constexpr int NPIX = B_ * N_ * N_;      // 2^20
static constexpr int LUT_ROWS = 83521;         // 17^4
static constexpr int SPAD = 83584;             // LUT_ROWS padded to 16B multiple
static constexpr int ST0 = 4913, ST1 = 289, ST2 = 17, ST3 = 1;

__device__ __forceinline__ float fixw(float v) {
    v = rintf(v * 127.0f);
    return fminf(fmaxf(v, -127.0f), 127.0f);
}

// (3,83521) -> int8 with 16B-aligned per-sampler stride SPAD
__global__ void fix_lut0_kernel(const float* __restrict__ in, char* __restrict__ out) {
    int t = blockIdx.x * blockDim.x + threadIdx.x;
    int s = blockIdx.y;
    if (t < LUT_ROWS) out[(size_t)s * SPAD + t] = (char)(int)fixw(in[(size_t)s * LUT_ROWS + t]);
}

__global__ void fix_lut1_kernel(const float4* __restrict__ in, char4* __restrict__ out, int n4) {
    int t = blockIdx.x * blockDim.x + threadIdx.x;
    if (t < n4) {
        float4 v = in[t];
        char4 o;
        o.x = (char)(int)fixw(v.x);
        o.y = (char)(int)fixw(v.y);
        o.z = (char)(int)fixw(v.z);
        o.w = (char)(int)fixw(v.w);
        out[t] = o;
    }
}

struct Simplex {
    int v[5];
    float w[5];   // pre-scaled by 1/16
};

// 4-D simplex lookup setup. floor/mod by 16 are exact in fp32 (pow-2); sort is a
// stable descending bubble network (ties -> zero-weight vertices, order-irrelevant).
__device__ __forceinline__ Simplex simplex4(float a, float b, float c, float d) {
    float fl0 = floorf(a * 0.0625f), fl1 = floorf(b * 0.0625f),
          fl2 = floorf(c * 0.0625f), fl3 = floorf(d * 0.0625f);
    float f[4] = { a - 16.0f * fl0, b - 16.0f * fl1, c - 16.0f * fl2, d - 16.0f * fl3 };
    int l0 = min(max((int)fl0, 0), 15);
    int l1 = min(max((int)fl1, 0), 15);
    int l2 = min(max((int)fl2, 0), 15);
    int l3 = min(max((int)fl3, 0), 15);
    int st[4] = { ST0, ST1, ST2, ST3 };
#define CSW(A, Bq) { if (f[A] < f[Bq]) { float tf = f[A]; f[A] = f[Bq]; f[Bq] = tf; \
                                         int ts = st[A]; st[A] = st[Bq]; st[Bq] = ts; } }
    CSW(0, 1) CSW(1, 2) CSW(2, 3) CSW(0, 1) CSW(1, 2) CSW(0, 1)
#undef CSW
    Simplex s;
    s.v[0] = l0 * ST0 + l1 * ST1 + l2 * ST2 + l3;
    s.v[1] = s.v[0] + st[0];
    s.v[2] = s.v[1] + st[1];
    s.v[3] = s.v[2] + st[2];
    s.v[4] = s.v[3] + st[3];
    s.w[0] = (16.0f - f[0]) * 0.0625f;
    s.w[1] = (f[0] - f[1]) * 0.0625f;
    s.w[2] = (f[1] - f[2]) * 0.0625f;
    s.w[3] = (f[2] - f[3]) * 0.0625f;
    s.w[4] = f[3] * 0.0625f;
    return s;
}

// Inverse tap map: which (di,dj) of rotation r reads clamped-neighborhood tap (a,c).
// (rotation r + edge-pad + VALID conv + rotate-back == clamped reads, orig frame)
__device__ __forceinline__ bool tap_for_r(int r, int a, int c, int& di, int& dj) {
    if (r == 0) { di = a - 2; dj = c - 2; return (a >= 2) && (c >= 2); }
    if (r == 1) { di = 2 - c; dj = a - 2; return (a >= 2) && (c <= 2); }
    if (r == 2) { di = 2 - a; dj = 2 - c; return (a <= 2) && (c <= 2); }
    di = c - 2; dj = 2 - a; return (a <= 2) && (c >= 2);
}

__device__ __forceinline__ void unpack4(int w, float* o) {
    o[0] = (float)((w << 24) >> 24);
    o[1] = (float)((w << 16) >> 24);
    o[2] = (float)((w << 8) >> 24);
    o[3] = (float)(w >> 24);
}

__global__ __launch_bounds__(1024, 4) void stage0_kernel(
    const float* __restrict__ x,       // (4,512,512), [0,1]
    const char* __restrict__ lut0q,    // (3,SPAD) int8 fixed, padded stride
    const float* __restrict__ samp0,   // (3,4,3,3)
    const float* __restrict__ sbias0,  // (3,4)
    float* __restrict__ x1)            // out: (4,512,512), integer-valued 0..255
{
    __shared__ char luts[SPAD];        // one sampler's LUT at a time (83.5KB)

    int tid = blockIdx.x * blockDim.x + threadIdx.x;
    int j = tid & (N_ - 1);
    int i = (tid >> 9) & (N_ - 1);
    int b = tid >> 18;
    const float* xb = x + (size_t)b * N_ * N_;

    float pred = 0.0f;
    for (int s = 0; s < 3; ++s) {
        // ---- stage LUT s into LDS
        __syncthreads();               // previous-iteration readers done
        {
            const int4* src = (const int4*)(lut0q + (size_t)s * SPAD);
            int4* dst = (int4*)luts;
            for (int t = threadIdx.x; t < SPAD / 16; t += 1024) dst[t] = src[t];
        }
        __syncthreads();

        const float* w  = samp0 + s * 36;
        const float* sb = sbias0 + s * 4;

        // tap-outer conv: only 1 pixel + 16 accumulators live
        float vals[4][4];
        #pragma unroll
        for (int r = 0; r < 4; ++r)
            #pragma unroll
            for (int ch = 0; ch < 4; ++ch) vals[r][ch] = 0.0f;
        #pragma unroll
        for (int a = 0; a < 5; ++a) {
            int ri = min(max(i - 2 + a, 0), N_ - 1);
            #pragma unroll
            for (int c = 0; c < 5; ++c) {
                int ci = min(max(j - 2 + c, 0), N_ - 1);
                float px = xb[ri * N_ + ci] * 255.0f;
                #pragma unroll
                for (int r = 0; r < 4; ++r) {
                    int di, dj;
                    if (tap_for_r(r, a, c, di, dj)) {
                        #pragma unroll
                        for (int ch = 0; ch < 4; ++ch)
                            vals[r][ch] += w[ch * 9 + di * 3 + dj] * px;
                    }
                }
            }
        }

        // per-rotation: simplex then 5 LDS byte-gathers (small live set, no arrays)
        float acc = 0.0f;
        #pragma unroll
        for (int r = 0; r < 4; ++r) {
            Simplex sx = simplex4(vals[r][0] + sb[0], vals[r][1] + sb[1],
                                  vals[r][2] + sb[2], vals[r][3] + sb[3]);
            float p0 = (float)luts[sx.v[0]];
            float p1 = (float)luts[sx.v[1]];
            float p2 = (float)luts[sx.v[2]];
            float p3 = (float)luts[sx.v[3]];
            float p4 = (float)luts[sx.v[4]];
            float o = sx.w[0] * p0 + sx.w[1] * p1 + sx.w[2] * p2
                    + sx.w[3] * p3 + sx.w[4] * p4;
            acc = rintf(acc + o);   // ste_round after each rotation
        }
        pred += acc;
    }
    x1[tid] = rintf(fminf(fmaxf(pred / 12.0f + 127.0f, 0.0f), 255.0f));
}

__global__ __launch_bounds__(256) void stage1_kernel(
    const float* __restrict__ x,       // original (4,512,512), [0,1]
    const float* __restrict__ x1,      // stage-0 out, 0..255
    const char* __restrict__ lut1q,    // (3,83521,16) int8 fixed
    const float* __restrict__ samp1,   // (3,4,3,3)
    const float* __restrict__ sbias1,  // (3,4)
    const float* __restrict__ resw1,   // (3,2,2)
    float* __restrict__ out)           // (4,2048,2048)
{
    int tid = blockIdx.x * blockDim.x + threadIdx.x;
    if (tid >= NPIX) return;
    int j = tid & (N_ - 1);
    int i = (tid >> 9) & (N_ - 1);
    int b = tid >> 18;
    const float* xb  = x  + (size_t)b * N_ * N_;
    const float* x1b = x1 + (size_t)b * N_ * N_;

    float tot[16];
    #pragma unroll
    for (int k = 0; k < 16; ++k) tot[k] = 0.0f;

    for (int s = 0; s < 3; ++s) {
        const float* w  = samp1 + s * 36;
        const float* sb = sbias1 + s * 4;
        const char* lut = lut1q + (size_t)s * LUT_ROWS * 16;
        float rw[4];
        #pragma unroll
        for (int ch = 0; ch < 4; ++ch)
            rw[ch] = fminf(fmaxf(resw1[s * 4 + ch], 0.0f), 1.0f);

        // ---- tap-outer conv: 2 live pixels + 32 accumulators (vc, vp)
        float vc[4][4], vp[4][4];
        #pragma unroll
        for (int r = 0; r < 4; ++r)
            #pragma unroll
            for (int ch = 0; ch < 4; ++ch) { vc[r][ch] = 0.0f; vp[r][ch] = 0.0f; }
        #pragma unroll
        for (int a = 0; a < 5; ++a) {
            int ri = min(max(i - 2 + a, 0), N_ - 1);
            #pragma unroll
            for (int c = 0; c < 5; ++c) {
                int ci = min(max(j - 2 + c, 0), N_ - 1);
                float pc = x1b[ri * N_ + ci];
                float pp = xb[ri * N_ + ci] * 255.0f;
                #pragma unroll
                for (int r = 0; r < 4; ++r) {
                    int di, dj;
                    if (tap_for_r(r, a, c, di, dj)) {
                        #pragma unroll
                        for (int ch = 0; ch < 4; ++ch) {
                            float wt = w[ch * 9 + di * 3 + dj];
                            vc[r][ch] += wt * pc;
                            vp[r][ch] += wt * pp;
                        }
                    }
                }
            }
        }

        // ---- gather/interp phase
        float acc[16];
        #pragma unroll
        for (int k = 0; k < 16; ++k) acc[k] = 0.0f;

        #pragma unroll
        for (int r = 0; r < 4; ++r) {
            float vals[4];
            #pragma unroll
            for (int ch = 0; ch < 4; ++ch)
                vals[ch] = rw[ch] * (vp[r][ch] + sb[ch])
                         + (1.0f - rw[ch]) * (vc[r][ch] + sb[ch]);
            Simplex sx = simplex4(vals[0], vals[1], vals[2], vals[3]);
            float oc[16];
            #pragma unroll
            for (int k = 0; k < 16; ++k) oc[k] = 0.0f;
            #pragma unroll
            for (int v = 0; v < 5; ++v) {
                const int4 q = *(const int4*)(lut + (size_t)sx.v[v] * 16);
                float p[16];
                unpack4(q.x, p); unpack4(q.y, p + 4);
                unpack4(q.z, p + 8); unpack4(q.w, p + 12);
                float wv = sx.w[v];
                #pragma unroll
                for (int k = 0; k < 16; ++k) oc[k] += wv * p[k];
            }
            // scatter rotated 4x4 sub-block into original-orientation accumulator
            #pragma unroll
            for (int u = 0; u < 4; ++u)
                #pragma unroll
                for (int v2 = 0; v2 < 4; ++v2) {
                    int k = 4 * u + v2;
                    int c = (r == 0) ? (4 * u + v2)
                          : (r == 1) ? (4 * (3 - v2) + u)
                          : (r == 2) ? (4 * (3 - u) + (3 - v2))
                                     : (4 * v2 + (3 - u));
                    acc[k] = rintf(acc[k] + oc[c]);   // ste_round per rotation
                }
        }
        #pragma unroll
        for (int k = 0; k < 16; ++k) tot[k] += acc[k];
    }

    float* ob = out + (size_t)b * N4_ * N4_ + (size_t)(i * 4) * N4_ + (j * 4);
    #pragma unroll
    for (int u = 0; u < 4; ++u) {
        float4 val;
        val.x = rintf(fminf(fmaxf(tot[4 * u + 0] / 3.0f, 0.0f), 255.0f)) * (1.0f / 255.0f);
        val.y = rintf(fminf(fmaxf(tot[4 * u + 1] / 3.0f, 0.0f), 255.0f)) * (1.0f / 255.0f);
        val.z = rintf(fminf(fmaxf(tot[4 * u + 2] / 3.0f, 0.0f), 255.0f)) * (1.0f / 255.0f);
        val.w = rintf(fminf(fmaxf(tot[4 * u + 3] / 3.0f, 0.0f), 255.0f)) * (1.0f / 255.0f);
        *(float4*)(ob + (size_t)u * N4_) = val;
    }
}

extern "C" void kernel_launch(void* const* d_in, const int* in_sizes, int n_in,
                              void* d_out, int out_size, void* d_ws, size_t ws_size,
                              hipStream_t stream) {
    const float* x      = (const float*)d_in[0];
    const float* lut0   = (const float*)d_in[1];
    const float* lut1   = (const float*)d_in[2];
    const float* samp0  = (const float*)d_in[3];
    const float* samp1  = (const float*)d_in[4];
    const float* sbias0 = (const float*)d_in[5];
    const float* sbias1 = (const float*)d_in[6];
    const float* resw1  = (const float*)d_in[7];
    float* out = (float*)d_out;
    char* ws   = (char*)d_ws;

    const int N_L1 = 3 * LUT_ROWS * 16;       // 4,009,008
    size_t off_x1 = 0;                        // 4 MB of floats
    size_t off_l0 = (size_t)NPIX * sizeof(float);
    size_t off_l1 = (off_l0 + (size_t)3 * SPAD + 15) & ~(size_t)15;

    float* x1 = (float*)(ws + off_x1);
    char* l0q = ws + off_l0;                  // (3, SPAD) padded
    char* l1q = ws + off_l1;

    const int threads = 256;

    dim3 g0((LUT_ROWS + threads - 1) / threads, 3);
    fix_lut0_kernel<<<g0, threads, 0, stream>>>(lut0, l0q);
    fix_lut1_kernel<<<(N_L1 / 4 + threads - 1) / threads, threads, 0, stream>>>(
        (const float4*)lut1, (char4*)l1q, N_L1 / 4);
    stage0_kernel<<<NPIX / 1024, 1024, 0, stream>>>(x, l0q, samp0, sbias0, x1);
    stage1_kernel<<<NPIX / threads, threads, 0, stream>>>(x, x1, l1q, samp1, sbias1, resw1, out);
}